// Round 8
// baseline (92.149 us; speedup 1.0000x reference)
//
#include <hip/hip_runtime.h>
#include <math.h>

#define NB 32
#define CC 64
#define LL 1024
#define EPS 1e-6f
#define SCALE 14.42695040888963f   // 10*log2(e): exp(10*s) == exp2(SCALE*s)

typedef __attribute__((ext_vector_type(8)))  __bf16 bf16x8;
typedef __attribute__((ext_vector_type(16))) float  f32x16;

#define GLB(p) ((__attribute__((address_space(1))) void*)(p))
#define LDS(p) ((__attribute__((address_space(3))) void*)(p))

// ws byte layout:
//   At      @ 0         (4 MB)   bf16 [32][1024][64]  rgb, normalized*SCALE, [l][c]
//   Bt      @ 4194304   (4 MB)   bf16 [32][1024][64]  ir, normalized, [l][c]
//   row_sum @ 8388608   (128 KB) f32[32768]
//   col_sum @ 8519680   (128 KB) f32[32768]
//   row_pk  @ 8650752   (128 KB) u32[32768]  (expbits&~1023)|(1023-j)
//   col_pk  @ 8781824   (128 KB) u32[32768]  (expbits&~1023)|(1023-i)
//   partial @ 8912896   (256 B)  f32[64] loss partials
// No zero-init: every stats word is direct-stored exactly once.

__global__ __launch_bounds__(256) void transpose_norm_kernel(
        const float* __restrict__ rgb, const float* __restrict__ ir,
        __bf16* __restrict__ At, __bf16* __restrict__ Bt) {
    __shared__ float tile[64][65];
    __shared__ float red[4][64];
    __shared__ float rn[64];

    const int t   = threadIdx.x;
    const int blk = blockIdx.x;
    const int in  = blk >> 9;
    const int b   = (blk >> 4) & 31;
    const int l0  = (blk & 15) << 6;
    const float* src = in ? ir : rgb;
    __bf16*      dst = in ? Bt : At;
    const float  sc  = in ? 1.0f : SCALE;   // fold exp2 prescale into rgb side

    const int ll = t & 63, cg = t >> 6;
    const float* sp = src + ((size_t)b << 16) + l0 + ll;
#pragma unroll
    for (int u = 0; u < 16; ++u) {
        int c = cg * 16 + u;
        tile[c][ll] = sp[(size_t)c << 10];
    }
    __syncthreads();

    float ssq = 0.f;
#pragma unroll
    for (int u = 0; u < 16; ++u) {
        float v = tile[cg * 16 + u][ll];
        ssq = fmaf(v, v, ssq);
    }
    red[cg][ll] = ssq;
    __syncthreads();
    if (t < 64) {
        float s = red[0][t] + red[1][t] + red[2][t] + red[3][t];
        rn[t] = sc / fmaxf(sqrtf(s), 1e-12f);
    }
    __syncthreads();

    const int lw  = t >> 2;
    const int cg2 = t & 3;
    const float r = rn[lw];
    bf16x8 v0, v1;
#pragma unroll
    for (int u = 0; u < 8; ++u)
        v0[u] = (__bf16)(tile[cg2 * 16 + u][lw] * r);
#pragma unroll
    for (int u = 0; u < 8; ++u)
        v1[u] = (__bf16)(tile[cg2 * 16 + 8 + u][lw] * r);
    size_t base = ((((size_t)b << 10) + l0 + lw) << 6) + cg2 * 16;
    *(bf16x8*)(dst + base)     = v0;
    *(bf16x8*)(dst + base + 8) = v1;
}

// Grid 512 = dir(2) x batch(32) x itile(8). 4 waves; wave w owns rows
// [i0+32w, +32) x all 1024 cols of S (dir 0) or S^T (dir 1; bitwise-identical
// values). 32x32x16 MFMA, 32 rows/wave (r7 lesson: per-wave B LDS traffic is
// fixed at cols*K*2B, so rows/wave is the lever on TOTAL LDS reads — halving
// wave count halves the ~8 us LDS-port floor). 256-row chunks, 2 buffers
// (64 KB), async global_load_lds (un-sinkable, r6/r7 lesson), 4 barriers.
//
// Layouts (32x32x16_bf16): A: row=lane&31, k=16kb+8(lane>>5)+j. B symmetric.
// C/D (HW-verified m74/m101): col=lane&31, row=(reg&3)+8(reg>>2)+4(lane>>5).
// LDS swizzle (global-side permute, free gather): seg s of row r lands at
// slot s^(r&7); fragment reads then hit each bank exactly 8x (b128 floor).
__global__ __launch_bounds__(256, 2) void gemm_stats_kernel(
        const __bf16* __restrict__ At, const __bf16* __restrict__ Bt,
        float* __restrict__ row_sum, unsigned* __restrict__ row_pk,
        float* __restrict__ col_sum, unsigned* __restrict__ col_pk) {
    __shared__ __bf16 Bs[2][16384];   // 2 x 32 KB (256 rows x 64 bf16)

    const int t   = threadIdx.x;
    const int blk = blockIdx.x;
    const int dir = blk >> 8;
    const int bb  = (blk >> 3) & 31;
    const int i0  = (blk & 7) << 7;
    const int w = t >> 6, lane = t & 63;
    const int c = lane & 31, kh = lane >> 5;

    const __bf16* Aarr = dir ? Bt : At;
    const __bf16* Barr = dir ? At : Bt;
    float*    osum = dir ? col_sum : row_sum;
    unsigned* opk  = dir ? col_pk  : row_pk;

    const size_t bbase = (size_t)bb << 16;
    const __bf16* Bg = Barr + bbase;

    // A fragments (held all kernel): row = i0+32w+c, k = 16kb + 8kh + j.
    const __bf16* Ap = Aarr + bbase + ((size_t)(i0 + 32 * w + c) << 6) + kh * 8;
    bf16x8 a[4];
#pragma unroll
    for (int kb = 0; kb < 4; ++kb) a[kb] = *(const bf16x8*)(Ap + kb * 16);

    // Staging geometry: 2048 slots x 16 B per chunk; thread covers rho*256+t.
    // slot -> row r = slot>>3, lds seg = slot&7, global seg = (slot&7)^(r&7).
    const int sr  = t >> 3;   // row contribution (0..31)
    const int ssl = t & 7;

    // stage chunk 0 -> Bs[0]
#pragma unroll
    for (int rho = 0; rho < 8; ++rho) {
        int r  = rho * 32 + sr;
        int sg = ssl ^ (r & 7);
        const __bf16* gp = Bg + ((size_t)r << 6) + sg * 8;
        __builtin_amdgcn_global_load_lds(GLB(gp),
                LDS(&Bs[0][(rho << 11) + (w << 9)]), 16, 0, 0);
    }

    float    rsum[16]; unsigned rpk[16];
#pragma unroll
    for (int g = 0; g < 16; ++g) { rsum[g] = 0.f; rpk[g] = 0u; }

    const int rb7 = c & 7;   // (lds row)&7 for this lane's B rows
    __syncthreads();   // chunk 0 ready

    for (int ch = 0; ch < 4; ++ch) {
        const int cur = ch & 1;
        if (ch < 3) {   // async-issue chunk ch+1 into the other buffer
#pragma unroll
            for (int rho = 0; rho < 8; ++rho) {
                int r  = rho * 32 + sr;
                int sg = ssl ^ (r & 7);
                const __bf16* gp = Bg + ((size_t)((ch + 1) * 256 + r) << 6) + sg * 8;
                __builtin_amdgcn_global_load_lds(GLB(gp),
                        LDS(&Bs[cur ^ 1][(rho << 11) + (w << 9)]), 16, 0, 0);
            }
        }
#pragma unroll
        for (int ctL = 0; ctL < 8; ++ctL) {
            const int lrow = ctL * 32 + c;          // LDS row = local col index
            const __bf16* pb = &Bs[cur][lrow << 6];
            f32x16 acc = (f32x16){0.f, 0.f, 0.f, 0.f, 0.f, 0.f, 0.f, 0.f,
                                  0.f, 0.f, 0.f, 0.f, 0.f, 0.f, 0.f, 0.f};
#pragma unroll
            for (int kb = 0; kb < 4; ++kb) {
                const int s_lds = ((2 * kb + kh) ^ rb7) << 3;
                bf16x8 b = *(const bf16x8*)(pb + s_lds);
                acc = __builtin_amdgcn_mfma_f32_32x32x16_bf16(a[kb], b, acc, 0, 0, 0);
            }
            const int col = ch * 256 + ctL * 32 + c;
            const unsigned jinv = 1023u - (unsigned)col;
#pragma unroll
            for (int g = 0; g < 16; ++g) {
                float e = __builtin_amdgcn_exp2f(acc[g]);   // SCALE folded into At
                unsigned p = (__float_as_uint(e) & 0xFFFFFC00u) | jinv;
                rsum[g] += e;
                if (p > rpk[g]) rpk[g] = p;
            }
        }
        __syncthreads();   // next chunk loaded AND buffer free to restage
    }

    // Butterfly over the 32 col-lanes (xor 1..16; bit5=kh group preserved).
#pragma unroll
    for (int s = 1; s < 32; s <<= 1) {
#pragma unroll
        for (int g = 0; g < 16; ++g) {
            rsum[g] += __shfl_xor(rsum[g], s, 64);
            unsigned o = (unsigned)__shfl_xor((int)rpk[g], s, 64);
            if (o > rpk[g]) rpk[g] = o;
        }
    }
    if (c == 0) {
#pragma unroll
        for (int g = 0; g < 16; ++g) {
            int row = i0 + 32 * w + 4 * kh + (g & 3) + 8 * (g >> 2);
            int idx = (bb << 10) + row;
            osum[idx] = rsum[g];
            opk[idx]  = rpk[g];
        }
    }
}

// Reference broadcasting: trailing /(sum+EPS) factors are indexed by ELEMENT
// position, not by argmax. Writes per-block partials (no atomics, no init).
__global__ __launch_bounds__(256) void loss_kernel2(
        const float* __restrict__ row_sum, const unsigned* __restrict__ row_pk,
        const float* __restrict__ col_sum, const unsigned* __restrict__ col_pk,
        float* __restrict__ partial) {
    int t = blockIdx.x * 256 + threadIdx.x;
    float acc = 0.f;
#pragma unroll
    for (int it = 0; it < 4; ++it) {
        int p = t + it * 16384;
        if (p < NB * LL) {
            unsigned pk2 = row_pk[p];
            float m2 = __uint_as_float(pk2 & 0xFFFFFC00u);
            int j = 1023 - (int)(pk2 & 1023u);
            float s2 = row_sum[p];
            float s1 = col_sum[p];
            unsigned pk1 = col_pk[(p & ~1023) + j];
            float m1 = __uint_as_float(pk1 & 0xFFFFFC00u);
            acc += logf((m2 / (s2 + EPS)) * (m1 / (s1 + EPS)));
        } else {
            int p2 = p - NB * LL;
            unsigned pk1 = col_pk[p2];
            float m1 = __uint_as_float(pk1 & 0xFFFFFC00u);
            int i = 1023 - (int)(pk1 & 1023u);
            float s1 = col_sum[p2];
            float s2 = row_sum[p2];
            unsigned pk2 = row_pk[(p2 & ~1023) + i];
            float m2 = __uint_as_float(pk2 & 0xFFFFFC00u);
            acc += logf((m1 / (s1 + EPS)) * (m2 / (s2 + EPS)));
        }
    }
#pragma unroll
    for (int off = 32; off > 0; off >>= 1) acc += __shfl_down(acc, off, 64);
    __shared__ float wsum[4];
    int lane = threadIdx.x & 63, w = threadIdx.x >> 6;
    if (lane == 0) wsum[w] = acc;
    __syncthreads();
    if (threadIdx.x == 0)
        partial[blockIdx.x] = wsum[0] + wsum[1] + wsum[2] + wsum[3];
}

__global__ void finalize_kernel(const float* __restrict__ partial,
                                float* __restrict__ out) {
    float v = partial[threadIdx.x];
#pragma unroll
    for (int off = 32; off > 0; off >>= 1) v += __shfl_down(v, off, 64);
    if (threadIdx.x == 0) out[0] = -v / (float)(2 * NB * LL);
}

extern "C" void kernel_launch(void* const* d_in, const int* in_sizes, int n_in,
                              void* d_out, int out_size, void* d_ws, size_t ws_size,
                              hipStream_t stream) {
    const float* rgb = (const float*)d_in[0];
    const float* ir  = (const float*)d_in[1];
    char* wsb = (char*)d_ws;

    __bf16*   At      = (__bf16*)(wsb);
    __bf16*   Bt      = (__bf16*)(wsb + 4194304);
    float*    row_sum = (float*)(wsb + 8388608);
    float*    col_sum = (float*)(wsb + 8519680);
    unsigned* row_pk  = (unsigned*)(wsb + 8650752);
    unsigned* col_pk  = (unsigned*)(wsb + 8781824);
    float*    partial = (float*)(wsb + 8912896);

    transpose_norm_kernel<<<1024, 256, 0, stream>>>(rgb, ir, At, Bt);
    gemm_stats_kernel<<<512, 256, 0, stream>>>(At, Bt, row_sum, row_pk,
                                               col_sum, col_pk);
    loss_kernel2<<<64, 256, 0, stream>>>(row_sum, row_pk, col_sum, col_pk, partial);
    finalize_kernel<<<1, 64, 0, stream>>>(partial, (float*)d_out);
}